// Round 9
// baseline (147.687 us; speedup 1.0000x reference)
//
#include <hip/hip_runtime.h>
#include <hip/hip_bf16.h>

// GAT residual block: N=50000, IN=128, H=4, C=32 (H*C=128), E=800000.
// Inputs fp32 (edge_index int32): x, edge_index, W, att_src, att_dst, bias, skip_W, skip_b
// Output: float32 [N,128]
//
// 5 dispatches:
//  memset(count)
//  K1 pre:    blocks 0..781: 4 edges/thread: rank[k] = count[d]++ (independent atomics);
//             blocks 782..813: wb = bf16([W; skip_W])
//  K2 scan:   49 blocks; each block reduces count[0 .. b*1024) for its prefix (coalesced),
//             then scans its own 1024-chunk -> rowptr. (blocksum kernel fused away)
//  K3 mfma+fill, role-interleaved via bijective shuffle p=(b*2501)%6250:
//     p<3125:  16-row strip, 4 waves x 64 cols, mfma_f32_16x16x32_bf16. Waves 0,1 ->
//              packed row xpr[d] = [a_src f32x4 | xp bf16x128] (stride 272B) + a_dst;
//              waves 2,3 -> skip = x@skip_W^T + skip_b + bias.
//     p>=3125: col[rowptr[d]+rank[k]] = src via nontemporal store (no atomics).
//  K4 gather: one wave per dst, unroll-8: acc += exp(e)*xp[src] from packed rows,
//             denom in same pass; out = elu(skip + acc/denom).
// Segment-max skipped (softmax shift invariance, |e| <~ 6).

#define NN 50000
#define EE 800000
#define FD 128
#define NEG_SLOPE 0.2f

#define ROWU 136                      // packed row stride in ushorts (272 B, 16B-aligned)
#define SCB 1024
#define NB_SC ((NN + SCB - 1) / SCB)  // 49
#define NB_PRE 782                    // ceil(800000 / (256*4))
#define NB_CONVW 32                   // 32768 / 4 / 256
#define NB_MFMA (NN / 16)             // 3125
#define NB_FILL (EE / 256)            // 3125
#define NB_FUSED (NB_MFMA + NB_FILL)  // 6250

typedef __attribute__((ext_vector_type(8))) short short8;   // 8 bf16 = 4 VGPR
typedef __attribute__((ext_vector_type(4))) float f32x4;

__device__ inline ushort f2b(float f) {
    __hip_bfloat16 h = __float2bfloat16(f);
    return *reinterpret_cast<ushort*>(&h);
}
__device__ inline float b2f(ushort u) {
    union { float f; unsigned int i; } c;
    c.i = ((unsigned int)u) << 16;
    return c.f;
}

// blocks [0, NB_PRE): rank capture (4 edges/thread); [NB_PRE, NB_PRE+NB_CONVW): W conv
__global__ __launch_bounds__(256) void gat_pre_kernel(
    const int* __restrict__ idx, int* __restrict__ count, int* __restrict__ rank,
    const float* __restrict__ W, const float* __restrict__ skip_W,
    ushort* __restrict__ wb)
{
    int b = blockIdx.x;
    if (b < NB_PRE) {
        int base = (b * 256 + threadIdx.x) * 4;
        if (base >= EE) return;
        int4 dd = *reinterpret_cast<const int4*>(idx + EE + base);
        int4 rr;
        rr.x = atomicAdd(&count[dd.x], 1);
        rr.y = atomicAdd(&count[dd.y], 1);
        rr.z = atomicAdd(&count[dd.z], 1);
        rr.w = atomicAdd(&count[dd.w], 1);
        *reinterpret_cast<int4*>(rank + base) = rr;
    } else {
        int i = ((b - NB_PRE) * 256 + threadIdx.x) * 4;   // < 32768
        int row = i >> 7;
        int colb = i & 127;
        const float* src = (row < 128) ? (W + row * FD + colb)
                                       : (skip_W + (row - 128) * FD + colb);
        float4 v = *reinterpret_cast<const float4*>(src);
        ushort4 o;
        o.x = f2b(v.x); o.y = f2b(v.y); o.z = f2b(v.z); o.w = f2b(v.w);
        *reinterpret_cast<ushort4*>(wb + i) = o;
    }
}

// 49 blocks; block b: prefix = sum(count[0 .. b*1024)) reduced in-block, then scan chunk
__global__ __launch_bounds__(1024) void gat_scan_kernel(
    const int* __restrict__ count, int* __restrict__ rowptr)
{
    __shared__ int ws[16];
    __shared__ int boff_s;
    int tid = threadIdx.x, lane = tid & 63, wv = tid >> 6;

    // phase A: block prefix
    int ps = 0;
    for (int i = tid; i < blockIdx.x * SCB; i += SCB) ps += count[i];
    #pragma unroll
    for (int off = 32; off; off >>= 1) ps += __shfl_down(ps, off, 64);
    if (lane == 0) ws[wv] = ps;
    __syncthreads();
    if (wv == 0) {
        int t = (lane < 16) ? ws[lane] : 0;
        #pragma unroll
        for (int off = 8; off; off >>= 1) t += __shfl_down(t, off, 64);
        if (lane == 0) boff_s = t;
    }
    __syncthreads();

    // phase B: scan own chunk
    int i = blockIdx.x * SCB + tid;
    int v = (i < NN) ? count[i] : 0;
    int incl = v;
    #pragma unroll
    for (int off = 1; off < 64; off <<= 1) {
        int t = __shfl_up(incl, off, 64);
        if (lane >= off) incl += t;
    }
    if (lane == 63) ws[wv] = incl;
    __syncthreads();
    if (wv == 0) {
        int t = (lane < 16) ? ws[lane] : 0;
        int winc = t;
        #pragma unroll
        for (int off = 1; off < 16; off <<= 1) {
            int u = __shfl_up(winc, off, 64);
            if (lane >= off) winc += u;
        }
        if (lane < 16) ws[lane] = winc - t;
    }
    __syncthreads();
    int excl = boff_s + ws[wv] + incl - v;
    if (i < NN) rowptr[i] = excl;
    if (blockIdx.x == 0 && tid == 0) rowptr[NN] = EE;
}

// fused, role-interleaved: p=(b*2501)%6250; p<3125 -> MFMA strip p; else fill chunk
__global__ __launch_bounds__(256) void gat_mfma_fill_kernel(
    const float* __restrict__ x, const ushort* __restrict__ wb,
    const float* __restrict__ att_src, const float* __restrict__ att_dst,
    const float* __restrict__ bias, const float* __restrict__ skip_b,
    ushort* __restrict__ xpr, float* __restrict__ a_dst, float* __restrict__ skip,
    const int* __restrict__ idx, const int* __restrict__ rank,
    const int* __restrict__ rowptr, int* __restrict__ col)
{
    const int p = (int)(((long long)blockIdx.x * 2501) % NB_FUSED);
    if (p >= NB_MFMA) {
        // ---- fill: no atomics, nontemporal scattered store ----
        int k = (p - NB_MFMA) * 256 + threadIdx.x;   // exact 800000
        int d = idx[EE + k];
        int pos = rowptr[d] + rank[k];
        __builtin_nontemporal_store(idx[k], &col[pos]);
        return;
    }

    // ---- MFMA strip p ----
    const int tid = threadIdx.x;
    const int w = tid >> 6;
    const int l = tid & 63;
    const int lrow = l & 15;
    const int lgrp = l >> 4;
    const int m0 = p * 16;
    const int is_skip = w >> 1;
    const int ncb = (w & 1) * 64;

    // B frags: wb row j = is_skip*128 + ncb + t*16 + lrow; k = kk*32 + lgrp*8 .. +8
    short8 bfrag[4][4];
    const ushort* wbase = wb + (size_t)(is_skip * 128 + ncb) * FD;
    #pragma unroll
    for (int t = 0; t < 4; ++t)
        #pragma unroll
        for (int kk = 0; kk < 4; ++kk)
            bfrag[t][kk] = *reinterpret_cast<const short8*>(
                wbase + (size_t)(t * 16 + lrow) * FD + kk * 32 + lgrp * 8);

    // A frags: fp32 x row m0+lrow, converted in-register
    short8 afrag[4];
    const float* xrow = x + (size_t)(m0 + lrow) * FD + lgrp * 8;
    #pragma unroll
    for (int kk = 0; kk < 4; ++kk) {
        float4 a0 = *reinterpret_cast<const float4*>(xrow + kk * 32);
        float4 a1 = *reinterpret_cast<const float4*>(xrow + kk * 32 + 4);
        short8 af;
        af[0] = f2b(a0.x); af[1] = f2b(a0.y); af[2] = f2b(a0.z); af[3] = f2b(a0.w);
        af[4] = f2b(a1.x); af[5] = f2b(a1.y); af[6] = f2b(a1.z); af[7] = f2b(a1.w);
        afrag[kk] = af;
    }

    f32x4 acc[4];
    #pragma unroll
    for (int t = 0; t < 4; ++t) acc[t] = (f32x4){0.f, 0.f, 0.f, 0.f};

    #pragma unroll
    for (int kk = 0; kk < 4; ++kk)
        #pragma unroll
        for (int t = 0; t < 4; ++t)
            acc[t] = __builtin_amdgcn_mfma_f32_16x16x32_bf16(
                afrag[kk], bfrag[t][kk], acc[t], 0, 0, 0);

    // C/D: element (row = 4*lgrp + r, col = lrow) of tile t; col_t = ncb + t*16 + lrow
    if (is_skip) {
        #pragma unroll
        for (int t = 0; t < 4; ++t) {
            int colt = ncb + t * 16 + lrow;
            float add = skip_b[colt] + bias[colt];
            #pragma unroll
            for (int r = 0; r < 4; ++r) {
                int row = m0 + lgrp * 4 + r;
                skip[(size_t)row * FD + colt] = acc[t][r] + add;
            }
        }
    } else {
        float as[4], ad[4];
        #pragma unroll
        for (int t = 0; t < 4; ++t) {
            int colt = ncb + t * 16 + lrow;
            as[t] = att_src[colt];
            ad[t] = att_dst[colt];
            #pragma unroll
            for (int r = 0; r < 4; ++r) {
                int row = m0 + lgrp * 4 + r;
                xpr[(size_t)row * ROWU + 8 + colt] = f2b(acc[t][r]);
            }
        }
        const int h0 = ncb >> 5;   // tiles 0,1 -> head h0; tiles 2,3 -> head h0+1
        #pragma unroll
        for (int r = 0; r < 4; ++r) {
            float p0 = acc[0][r] * as[0] + acc[1][r] * as[1];
            float p1 = acc[2][r] * as[2] + acc[3][r] * as[3];
            float q0 = acc[0][r] * ad[0] + acc[1][r] * ad[1];
            float q1 = acc[2][r] * ad[2] + acc[3][r] * ad[3];
            #pragma unroll
            for (int m = 1; m < 16; m <<= 1) {
                p0 += __shfl_xor(p0, m, 64);
                p1 += __shfl_xor(p1, m, 64);
                q0 += __shfl_xor(q0, m, 64);
                q1 += __shfl_xor(q1, m, 64);
            }
            if (lrow == 0) {
                int row = m0 + lgrp * 4 + r;
                float* arow = reinterpret_cast<float*>(xpr + (size_t)row * ROWU);
                arow[h0]     = p0;
                arow[h0 + 1] = p1;
                a_dst[(size_t)row * 4 + h0]     = q0;
                a_dst[(size_t)row * 4 + h0 + 1] = q1;
            }
        }
    }
}

// one wave per dst node; lane owns channels (2*lane, 2*lane+1); head = lane>>4
__global__ __launch_bounds__(256) void gat_gather_kernel(
    const int* __restrict__ rowptr, const int* __restrict__ col,
    const float* __restrict__ a_dst, const ushort* __restrict__ xpr,
    const float* __restrict__ skip, float* __restrict__ out)
{
    int wid = (blockIdx.x * 256 + threadIdx.x) >> 6;
    const int d = __builtin_amdgcn_readfirstlane(wid);   // wave-uniform -> SGPR
    int lane = threadIdx.x & 63;
    const int h = lane >> 4;
    const int ch = lane * 2;
    const float ad = a_dst[(size_t)d * 4 + h];
    const int beg = rowptr[d], end = rowptr[d + 1];
    float2 sk = *reinterpret_cast<const float2*>(skip + (size_t)d * FD + ch);

    float accx = 0.f, accy = 0.f, asum = 0.f;
    int j = beg;
    for (; j + 8 <= end; j += 8) {
        int s[8];
        float e[8];
        ushort2 xv[8];
        #pragma unroll
        for (int i = 0; i < 8; ++i) s[i] = col[j + i];
        #pragma unroll
        for (int i = 0; i < 8; ++i) {
            const ushort* row = xpr + (size_t)s[i] * ROWU;
            e[i] = reinterpret_cast<const float*>(row)[h] + ad;
            xv[i] = *reinterpret_cast<const ushort2*>(row + 8 + ch);
        }
        #pragma unroll
        for (int i = 0; i < 8; ++i) {
            float ei = e[i];
            ei = ei > 0.f ? ei : NEG_SLOPE * ei;
            float pi = __expf(ei);
            asum += pi;
            accx += pi * b2f(xv[i].x);
            accy += pi * b2f(xv[i].y);
        }
    }
    for (; j < end; ++j) {
        int s = col[j];
        const ushort* row = xpr + (size_t)s * ROWU;
        float e = reinterpret_cast<const float*>(row)[h] + ad;
        ushort2 xv = *reinterpret_cast<const ushort2*>(row + 8 + ch);
        e = e > 0.f ? e : NEG_SLOPE * e;
        float pe = __expf(e);
        asum += pe;
        accx += pe * b2f(xv.x);
        accy += pe * b2f(xv.y);
    }
    float inv = 1.f / (asum + 1e-16f);
    float r0 = sk.x + accx * inv;
    float r1 = sk.y + accy * inv;
    r0 = r0 > 0.f ? r0 : expm1f(r0);
    r1 = r1 > 0.f ? r1 : expm1f(r1);
    *reinterpret_cast<float2*>(out + (size_t)d * FD + ch) = make_float2(r0, r1);
}

extern "C" void kernel_launch(void* const* d_in, const int* in_sizes, int n_in,
                              void* d_out, int out_size, void* d_ws, size_t ws_size,
                              hipStream_t stream)
{
    const float* x       = (const float*)d_in[0];
    const int*   idx     = (const int*)d_in[1];
    const float* W       = (const float*)d_in[2];
    const float* att_src = (const float*)d_in[3];
    const float* att_dst = (const float*)d_in[4];
    const float* bias    = (const float*)d_in[5];
    const float* skip_W  = (const float*)d_in[6];
    const float* skip_b  = (const float*)d_in[7];
    float*       out     = (float*)d_out;

    float*  ws     = (float*)d_ws;
    float*  skip   = ws;                         // 6,400,000 f32
    float*  a_dst  = ws + 6400000;               //   200,000 f32
    int*    count  = (int*)(ws + 6600000);       //    50,000 i32
    int*    rowptr = (int*)(ws + 6652000);       //    50,001 i32
    int*    col    = (int*)(ws + 6756000);       //   800,000 i32
    int*    rank   = (int*)(ws + 7556000);       //   800,000 i32
    ushort* xpr    = (ushort*)(ws + 8400000);    // 6,800,000 u16 (packed rows, 272B)
    ushort* wb     = (ushort*)(ws + 11900000);   //    32,768 u16
    // total ~48 MB

    hipMemsetAsync(count, 0, (size_t)NN * sizeof(int), stream);

    gat_pre_kernel<<<NB_PRE + NB_CONVW, 256, 0, stream>>>(idx, count, rank, W, skip_W, wb);

    gat_scan_kernel<<<NB_SC, SCB, 0, stream>>>(count, rowptr);

    gat_mfma_fill_kernel<<<NB_FUSED, 256, 0, stream>>>(
        x, wb, att_src, att_dst, bias, skip_b, xpr, a_dst, skip,
        idx, rank, rowptr, col);

    gat_gather_kernel<<<(NN * 64) / 256, 256, 0, stream>>>(
        rowptr, col, a_dst, xpr, skip, out);
}